// Round 1
// baseline (164.354 us; speedup 1.0000x reference)
//
#include <hip/hip_runtime.h>
#include <hip/hip_bf16.h>
#include <cstdint>

#define HDIM 256
#define MT   128      // feature rows per block
#define BD   64       // d (ex rows) per K-loop iteration
#define NDSPLIT 16    // D is split across this many blocks per row-tile

typedef short bf16x8 __attribute__((ext_vector_type(8)));
typedef float f32x4  __attribute__((ext_vector_type(4)));

typedef const __attribute__((address_space(1))) short as1_short;
typedef __attribute__((address_space(3))) short as3_short;

static __device__ __forceinline__ short f2bf(float x) {
    union { float f; uint32_t u; } v; v.f = x;
    uint32_t u = v.u;
    uint32_t r = (u + 0x7fffu + ((u >> 16) & 1u)) >> 16;
    return (short)r;
}

// ---- prep 1: row-wise L2 normalize fp32 -> bf16, one wave per row (H=256) ----
__global__ __launch_bounds__(256) void nrm_kernel(const float* __restrict__ src,
                                                  short* __restrict__ dst, int rows) {
    int wv = threadIdx.x >> 6;
    int lane = threadIdx.x & 63;
    int row = blockIdx.x * 4 + wv;
    if (row >= rows) return;
    const float4 v = *(const float4*)(src + (size_t)row * HDIM + lane * 4);
    float ss = v.x * v.x + v.y * v.y + v.z * v.z + v.w * v.w;
    #pragma unroll
    for (int m = 1; m < 64; m <<= 1) ss += __shfl_xor(ss, m, 64);
    float scale = 1.0f / fmaxf(sqrtf(ss), 1e-12f);
    short4 o;
    o.x = f2bf(v.x * scale); o.y = f2bf(v.y * scale);
    o.z = f2bf(v.z * scale); o.w = f2bf(v.w * scale);
    *(short4*)(dst + (size_t)row * HDIM + lane * 4) = o;
}

// ---- prep 2: transpose class reps to [32][D] bf16 (pad c>=C with 0) + zero out ----
__global__ __launch_bounds__(256) void prep2_kernel(const float* __restrict__ reps,
                                                    short* __restrict__ rt,
                                                    float* __restrict__ out, int outN,
                                                    int D, int C) {
    int tid = blockIdx.x * blockDim.x + threadIdx.x;   // 0 .. D-1 (grid sized for D)
    int nthr = gridDim.x * blockDim.x;
    for (int i = tid; i < outN; i += nthr) out[i] = 0.0f;
    if (tid < D) {
        for (int c = 0; c < 32; ++c) {
            float v = (c < C) ? reps[(size_t)tid * C + c] : 0.0f;
            rt[(size_t)c * D + tid] = f2bf(v);
        }
    }
}

// ---- fused: S = Fn @ En^T (MFMA), a = sign(s)|s|^p, intensity += rowsum(a),
//      echo += a @ R (MFMA via LDS round-trip) ----
__global__ __launch_bounds__(256) void fused_kernel(const short* __restrict__ Fn,
                                                    const short* __restrict__ En,
                                                    const short* __restrict__ Rt,
                                                    const int* __restrict__ pptr,
                                                    float* __restrict__ echo,
                                                    float* __restrict__ inten,
                                                    int N, int D, int C, int Dchunk) {
    __shared__ __align__(16) short lds_en[BD * HDIM];     // 32 KB, XOR-swizzled chunks
    __shared__ __align__(16) short abuf[4][2][16][72];    // 18 KB, stride 144B (=4 banks offset/row)

    const int tid  = threadIdx.x;
    const int lane = tid & 63;
    const int wv   = tid >> 6;
    const int q    = lane >> 4;     // quad 0..3
    const int l    = lane & 15;
    const int p    = pptr[0];

    const int Mbase = blockIdx.y * MT;
    const int dbase = blockIdx.x * Dchunk;

    const f32x4 zf = {0.0f, 0.0f, 0.0f, 0.0f};

    // A fragments for this wave's 32 rows (2 sub-blocks of 16), K=256 in 8 steps.
    // A layout (16x16x32): A[m = lane&15][k = ks*32 + q*8 + j]
    bf16x8 afrag[2][8];
    #pragma unroll
    for (int mb = 0; mb < 2; ++mb) {
        const short* rowp = Fn + (size_t)(Mbase + wv * 32 + mb * 16 + l) * HDIM;
        #pragma unroll
        for (int ks = 0; ks < 8; ++ks)
            afrag[mb][ks] = *(const bf16x8*)(rowp + ks * 32 + q * 8);
    }

    f32x4 echo_acc[2][2];
    f32x4 intens[2];
    #pragma unroll
    for (int mb = 0; mb < 2; ++mb) {
        intens[mb] = zf;
        echo_acc[mb][0] = zf; echo_acc[mb][1] = zf;
    }

    const int iters = Dchunk / BD;
    for (int it = 0; it < iters; ++it) {
        const int d0 = dbase + it * BD;

        __syncthreads();   // previous iteration's LDS reads done before restage
        // Stage En tile (64 rows x 512B) via global_load_lds, 16B chunks.
        // LDS slot (row, sc) holds global chunk (row, sc ^ (row&7)).
        #pragma unroll
        for (int i = 0; i < 8; ++i) {
            int L = i * 256 + tid;          // linear 16B-chunk slot 0..2047
            int row = L >> 5;
            int sc  = L & 31;
            int cdat = sc ^ (row & 7);
            const short* g = En + (size_t)(d0 + row) * HDIM + cdat * 8;
            as3_short* lp = (as3_short*)(lds_en + (size_t)(i * 256 + wv * 64) * 8);
            __builtin_amdgcn_global_load_lds((as1_short*)g, lp, 16, 0, 0);
        }
        __syncthreads();

        // First GEMM: S tile 32x64 per wave (2 mb x 4 cb of 16x16), K=256
        f32x4 s[2][4];
        #pragma unroll
        for (int mb = 0; mb < 2; ++mb)
            #pragma unroll
            for (int cb = 0; cb < 4; ++cb) s[mb][cb] = zf;

        #pragma unroll
        for (int ks = 0; ks < 8; ++ks) {
            #pragma unroll
            for (int cb = 0; cb < 4; ++cb) {
                int row  = cb * 16 + l;                 // d within tile
                int slot = (ks * 4 + q) ^ (row & 7);    // swizzled chunk
                bf16x8 bf = *(const bf16x8*)(lds_en + row * HDIM + slot * 8);
                s[0][cb] = __builtin_amdgcn_mfma_f32_16x16x32_bf16(afrag[0][ks], bf, s[0][cb], 0, 0, 0);
                s[1][cb] = __builtin_amdgcn_mfma_f32_16x16x32_bf16(afrag[1][ks], bf, s[1][cb], 0, 0, 0);
            }
        }

        // Activation + intensity + write a-tile (bf16) for second GEMM.
        // C layout: value (row = q*4+r, col = cb*16+l)
        #pragma unroll
        for (int mb = 0; mb < 2; ++mb) {
            #pragma unroll
            for (int cb = 0; cb < 4; ++cb) {
                #pragma unroll
                for (int r = 0; r < 4; ++r) {
                    float sv = s[mb][cb][r];
                    float a;
                    if (p == 3)      a = sv * sv * sv;
                    else if (p == 1) a = sv;
                    else if (p == 2) a = sv * fabsf(sv);
                    else             a = copysignf(powf(fabsf(sv), (float)p), sv);
                    intens[mb][r] += a;
                    abuf[wv][mb][q * 4 + r][cb * 16 + l] = f2bf(a);
                }
            }
        }
        // (same-wave LDS write->read; compiler inserts lgkmcnt waits)

        // Second GEMM: echo_acc += a_tile(16x64) @ R_tile(64x32), per mb
        #pragma unroll
        for (int mb = 0; mb < 2; ++mb) {
            bf16x8 a2[2];
            #pragma unroll
            for (int kk = 0; kk < 2; ++kk)
                a2[kk] = *(const bf16x8*)(&abuf[wv][mb][l][kk * 32 + q * 8]);
            #pragma unroll
            for (int nb = 0; nb < 2; ++nb) {
                #pragma unroll
                for (int kk = 0; kk < 2; ++kk) {
                    const short* bp = Rt + (size_t)(nb * 16 + l) * D + d0 + kk * 32 + q * 8;
                    bf16x8 b2 = *(const bf16x8*)bp;
                    echo_acc[mb][nb] = __builtin_amdgcn_mfma_f32_16x16x32_bf16(a2[kk], b2, echo_acc[mb][nb], 0, 0, 0);
                }
            }
        }
    }

    // Final: reduce + atomics
    #pragma unroll
    for (int mb = 0; mb < 2; ++mb) {
        #pragma unroll
        for (int r = 0; r < 4; ++r) {
            float v = intens[mb][r];
            v += __shfl_xor(v, 1); v += __shfl_xor(v, 2);
            v += __shfl_xor(v, 4); v += __shfl_xor(v, 8);
            if (l == 0)
                atomicAdd(inten + Mbase + wv * 32 + mb * 16 + q * 4 + r, v);
        }
        #pragma unroll
        for (int nb = 0; nb < 2; ++nb) {
            int c = nb * 16 + l;
            if (c < C) {
                #pragma unroll
                for (int r = 0; r < 4; ++r) {
                    int grow = Mbase + wv * 32 + mb * 16 + q * 4 + r;
                    atomicAdd(echo + (size_t)grow * C + c, echo_acc[mb][nb][r]);
                }
            }
        }
    }
}

extern "C" void kernel_launch(void* const* d_in, const int* in_sizes, int n_in,
                              void* d_out, int out_size, void* d_ws, size_t ws_size,
                              hipStream_t stream) {
    const int N = in_sizes[0] / HDIM;       // 4096
    const int D = in_sizes[1] / HDIM;       // 16384
    const int C = in_sizes[2] / D;          // 28

    const float* feat = (const float*)d_in[0];
    const float* exf  = (const float*)d_in[1];
    const float* reps = (const float*)d_in[2];
    const int*   p    = (const int*)d_in[3];

    short* Fn = (short*)d_ws;
    short* En = Fn + (size_t)N * HDIM;
    short* Rt = En + (size_t)D * HDIM;

    float* echo  = (float*)d_out;
    float* inten = echo + (size_t)N * C;

    hipLaunchKernelGGL(nrm_kernel, dim3(N / 4), dim3(256), 0, stream, feat, Fn, N);
    hipLaunchKernelGGL(nrm_kernel, dim3(D / 4), dim3(256), 0, stream, exf, En, D);
    hipLaunchKernelGGL(prep2_kernel, dim3(D / 256), dim3(256), 0, stream,
                       reps, Rt, (float*)d_out, N * C + N, D, C);

    const int Dchunk = D / NDSPLIT;
    hipLaunchKernelGGL(fused_kernel, dim3(NDSPLIT, N / MT), dim3(256), 0, stream,
                       Fn, En, Rt, p, echo, inten, N, D, C, Dchunk);
}